// Round 9
// baseline (14262.427 us; speedup 1.0000x reference)
//
#include <hip/hip_runtime.h>
#include <math.h>

#define T_SEQ 4096
#define I_DIM 1024
#define H_DIM 2048
#define O_DIM 512
#define G4    8192   // 4*H

// ---------------------------------------------------------------------------
// Phase 1: xg[t, perm(r)] = sum_k input[t,k]*W_ih[r,k] + b_ih[r] + b_hh[r]
// perm(r): r = g*2048 + 8*q + j  ->  t*8192 + q*32 + g*8 + j
// so that LSTM block b (=q) reads its 32 gate values contiguously.
// Tiled fp32 GEMM: 128x128 tile, BK=16, 256 threads, 8x8 microtile.
// ---------------------------------------------------------------------------
__global__ __launch_bounds__(256) void gemm_xg(
    const float* __restrict__ A, const float* __restrict__ W,
    const float* __restrict__ b_ih, const float* __restrict__ b_hh,
    float* __restrict__ xg)
{
  __shared__ __align__(16) float As[16][132];
  __shared__ __align__(16) float Bs[16][132];
  const int tid = threadIdx.x;
  const int t0 = blockIdx.y * 128;
  const int r0 = blockIdx.x * 128;
  const int tx = tid & 15, ty = tid >> 4;

  float acc[8][8];
  #pragma unroll
  for (int i = 0; i < 8; ++i)
    #pragma unroll
    for (int j = 0; j < 8; ++j) acc[i][j] = 0.f;

  for (int k0 = 0; k0 < I_DIM; k0 += 16) {
    #pragma unroll
    for (int i = 0; i < 2; ++i) {
      int lin = tid + i * 256;     // 0..511
      int row = lin >> 2;          // 0..127
      int kq  = (lin & 3) << 2;    // 0,4,8,12
      float4 va = *(const float4*)&A[(size_t)(t0 + row) * I_DIM + k0 + kq];
      As[kq+0][row] = va.x; As[kq+1][row] = va.y; As[kq+2][row] = va.z; As[kq+3][row] = va.w;
      float4 vb = *(const float4*)&W[(size_t)(r0 + row) * I_DIM + k0 + kq];
      Bs[kq+0][row] = vb.x; Bs[kq+1][row] = vb.y; Bs[kq+2][row] = vb.z; Bs[kq+3][row] = vb.w;
    }
    __syncthreads();
    #pragma unroll
    for (int kk = 0; kk < 16; ++kk) {
      float4 a0 = *(const float4*)&As[kk][ty*8];
      float4 a1 = *(const float4*)&As[kk][ty*8+4];
      float4 b0 = *(const float4*)&Bs[kk][tx*8];
      float4 b1 = *(const float4*)&Bs[kk][tx*8+4];
      float av[8] = {a0.x,a0.y,a0.z,a0.w,a1.x,a1.y,a1.z,a1.w};
      float bv[8] = {b0.x,b0.y,b0.z,b0.w,b1.x,b1.y,b1.z,b1.w};
      #pragma unroll
      for (int i = 0; i < 8; ++i)
        #pragma unroll
        for (int j = 0; j < 8; ++j)
          acc[i][j] = fmaf(av[i], bv[j], acc[i][j]);
    }
    __syncthreads();
  }

  const int rbase = r0 + tx * 8;          // multiple of 8
  const int g = rbase >> 11;              // gate 0..3 (constant over 8 cols)
  const int q = (rbase & 2047) >> 3;      // 8-row group = LSTM block id
  float bias[8];
  #pragma unroll
  for (int j = 0; j < 8; ++j) bias[j] = b_ih[rbase + j] + b_hh[rbase + j];
  #pragma unroll
  for (int i = 0; i < 8; ++i) {
    int t = t0 + ty * 8 + i;
    float* dst = &xg[(size_t)t * G4 + q * 32 + g * 8];
    float4 o0 = make_float4(acc[i][0]+bias[0], acc[i][1]+bias[1], acc[i][2]+bias[2], acc[i][3]+bias[3]);
    float4 o1 = make_float4(acc[i][4]+bias[4], acc[i][5]+bias[5], acc[i][6]+bias[6], acc[i][7]+bias[7]);
    *(float4*)&dst[0] = o0;
    *(float4*)&dst[4] = o1;
  }
}

// fast activations (lane 0 only, but on the serial critical path)
__device__ __forceinline__ float sigf(float x) {
  return 1.f / (1.f + __expf(-x));
}
__device__ __forceinline__ float tanh_fast(float x) {
  return 1.f - 2.f / (__expf(2.f * x) + 1.f);   // saturates correctly
}

// ---------------------------------------------------------------------------
// Phase 2: persistent LSTM recurrence, self-announcing (value,tag) pairs,
// NREP-way replicated (round-5 structure) + weights ACTUALLY in registers.
// Round-8 lesson: a float[128] ARRAY went to scratch (alloca never
// promoted; VGPR stayed 88) -> the t-loop kept re-reading 64 MB/step of
// weights from L2/LLC (~24 TB/s = the real bottleneck since round 2).
// Fix: 32 individually NAMED float4 variables (no array, no SROA needed),
// each component pinned once with a scalar asm "+v" -> defs are opaque
// asm outputs, remat-from-memory illegal, ~170 live VGPRs < 256 budget
// (LDS already caps occupancy at 2 waves/SIMD, so no occupancy cost).
// ---------------------------------------------------------------------------
__global__ __launch_bounds__(512, 2) void lstm_seq(
    const float* __restrict__ W_hh, const float* __restrict__ xg,
    uint2* __restrict__ hbuf, int nrep)
{
  __shared__ __align__(16) float smem[21000];  // 84000 B -> forces 1 block/CU
  float* hsh = smem;                           // 2 x 2048 broadcast buffers

  const int tid  = threadIdx.x;
  const int b    = blockIdx.x;     // 0..255
  const int lane = tid & 63;
  const int w    = tid >> 6;       // wave id = h element index within block
  const int pstr = nrep << 11;     // pairs per parity
  const int myrep = b & (nrep - 1);

  // Weights: 4 gate rows of h-element 8b+w; cols 4*lane + 256*k, k=0..7.
  // 32 NAMED float4s, loaded once, pinned into VGPRs.
  const float* wb0 = &W_hh[(size_t)(0 * H_DIM + 8 * b + w) * H_DIM + 4 * lane];
  const float* wb1 = &W_hh[(size_t)(1 * H_DIM + 8 * b + w) * H_DIM + 4 * lane];
  const float* wb2 = &W_hh[(size_t)(2 * H_DIM + 8 * b + w) * H_DIM + 4 * lane];
  const float* wb3 = &W_hh[(size_t)(3 * H_DIM + 8 * b + w) * H_DIM + 4 * lane];

#define WROW(G) \
  float4 w##G##0 = *(const float4*)(wb##G +    0); \
  float4 w##G##1 = *(const float4*)(wb##G +  256); \
  float4 w##G##2 = *(const float4*)(wb##G +  512); \
  float4 w##G##3 = *(const float4*)(wb##G +  768); \
  float4 w##G##4 = *(const float4*)(wb##G + 1024); \
  float4 w##G##5 = *(const float4*)(wb##G + 1280); \
  float4 w##G##6 = *(const float4*)(wb##G + 1536); \
  float4 w##G##7 = *(const float4*)(wb##G + 1792);
  WROW(0) WROW(1) WROW(2) WROW(3)

#define PIN4(V) asm volatile("" : "+v"(V.x), "+v"(V.y), "+v"(V.z), "+v"(V.w));
#define PINROW(G) \
  PIN4(w##G##0) PIN4(w##G##1) PIN4(w##G##2) PIN4(w##G##3) \
  PIN4(w##G##4) PIN4(w##G##5) PIN4(w##G##6) PIN4(w##G##7)
  PINROW(0) PINROW(1) PINROW(2) PINROW(3)

  float c_reg = 0.f;          // cell state (lane 0 of each wave)
  bool gaveup = false;        // hang safety valve

  // preload xg for t = 0 (uniform addresses; only lane 0 consumes)
  const float* xp0 = &xg[(size_t)0 * G4 + b * 32 + w];
  float xgi = xp0[0], xgf = xp0[8], xgg = xp0[16], xgo = xp0[24];

  for (int t = 0; t < T_SEQ; ++t) {
    const uint2* hb = hbuf + (t & 1) * pstr + (myrep << 11);  // my replica of h_t
    const unsigned tag = (unsigned)t;

    // 1) poll my 4 pairs (16B + 16B) until all 4 tags == t
    const uint2* a0 = hb + 256 * w + 4 * lane;
    uint4 f0, f1;
    int tries = 0;
    for (;;) {
      asm volatile("global_load_dwordx4 %0, %2, off sc0 sc1\n\t"
                   "global_load_dwordx4 %1, %3, off sc0 sc1\n\t"
                   "s_waitcnt vmcnt(0)"
                   : "=&v"(f0), "=&v"(f1)
                   : "v"(a0), "v"(a0 + 2)
                   : "memory");
      bool ok = (f0.y == tag) & (f0.w == tag) & (f1.y == tag) & (f1.w == tag);
      if (__all(ok) || gaveup) break;
      if (++tries > (1 << 17)) { gaveup = true; break; }
    }

    // 2) broadcast values into this step's LDS buffer
    float* hd = hsh + ((t & 1) << 11);
    float4 hv4 = make_float4(__uint_as_float(f0.x), __uint_as_float(f0.z),
                             __uint_as_float(f1.x), __uint_as_float(f1.z));
    *(float4*)&hd[256 * w + 4 * lane] = hv4;

    // prefetch xg for step t+1 (independent; consumed at loop tail so the
    // compiler's waitcnt for it lands off the poll path)
    float nxi = 0.f, nxf = 0.f, nxg = 0.f, nxo = 0.f;
    if (t + 1 < T_SEQ) {
      const float* xp = &xg[(size_t)(t + 1) * G4 + b * 32 + w];
      nxi = xp[0]; nxf = xp[8]; nxg = xp[16]; nxo = xp[24];
    }

    __syncthreads();   // the ONE barrier per step

    // 3) dot products: 4 gate rows x 32 cols per lane, weights in VGPRs
    float s0 = 0.f, s1 = 0.f, s2 = 0.f, s3 = 0.f;
#define DOTK(K) { \
    float4 hv = *(const float4*)&hd[4 * lane + 256 * K]; \
    s0 = fmaf(w0##K.x, hv.x, s0); s0 = fmaf(w0##K.y, hv.y, s0); \
    s0 = fmaf(w0##K.z, hv.z, s0); s0 = fmaf(w0##K.w, hv.w, s0); \
    s1 = fmaf(w1##K.x, hv.x, s1); s1 = fmaf(w1##K.y, hv.y, s1); \
    s1 = fmaf(w1##K.z, hv.z, s1); s1 = fmaf(w1##K.w, hv.w, s1); \
    s2 = fmaf(w2##K.x, hv.x, s2); s2 = fmaf(w2##K.y, hv.y, s2); \
    s2 = fmaf(w2##K.z, hv.z, s2); s2 = fmaf(w2##K.w, hv.w, s2); \
    s3 = fmaf(w3##K.x, hv.x, s3); s3 = fmaf(w3##K.y, hv.y, s3); \
    s3 = fmaf(w3##K.z, hv.z, s3); s3 = fmaf(w3##K.w, hv.w, s3); }
    DOTK(0) DOTK(1) DOTK(2) DOTK(3) DOTK(4) DOTK(5) DOTK(6) DOTK(7)

    // butterfly reduce 4 values across 64 lanes
    #pragma unroll
    for (int sh = 32; sh >= 1; sh >>= 1) {
      s0 += __shfl_xor(s0, sh, 64);
      s1 += __shfl_xor(s1, sh, 64);
      s2 += __shfl_xor(s2, sh, 64);
      s3 += __shfl_xor(s3, sh, 64);
    }

    // 4) lane 0: gate math + nrep packed (value, tag) stores (one/replica)
    if (lane == 0) {
      float iv = sigf(s0 + xgi);
      float fv = sigf(s1 + xgf);
      float gv = tanh_fast(s2 + xgg);
      float ov = sigf(s3 + xgo);
      c_reg = fv * c_reg + iv * gv;
      float hv = ov * tanh_fast(c_reg);
      uint2 pv;
      pv.x = __float_as_uint(hv);
      pv.y = (unsigned)(t + 1);
      uint2* dst = hbuf + ((t + 1) & 1) * pstr + 8 * b + w;
      for (int r = 0; r < nrep; ++r) {
        asm volatile("global_store_dwordx2 %0, %1, off sc0 sc1"
                     :: "v"(dst), "v"(pv) : "memory");
        dst += 2048;
      }
    }

    xgi = nxi; xgf = nxf; xgg = nxg; xgo = nxo;
  }
}

// ---------------------------------------------------------------------------
// Phase 3: out[o] = h_last . W_lin[o,:] + b_lin[o]. One wave per output.
// h_last = values of replica-0 pairs at parity 0 (step 4095 writes par 0).
// ---------------------------------------------------------------------------
__global__ __launch_bounds__(256) void proj_out(
    const float* __restrict__ W_lin, const float* __restrict__ b_lin,
    const uint2* __restrict__ hpairs, float* __restrict__ out)
{
  const int tid = threadIdx.x;
  const int lane = tid & 63;
  const int w4 = tid >> 6;
  const int o = blockIdx.x * 4 + w4;
  const float* wr = &W_lin[(size_t)o * H_DIM + 4 * lane];
  float s = 0.f;
  #pragma unroll
  for (int k = 0; k < 8; ++k) {
    float4 wv = *(const float4*)&wr[256 * k];
    uint4 p0 = *(const uint4*)&hpairs[4 * lane + 256 * k];       // v,t,v,t
    uint4 p1 = *(const uint4*)&hpairs[4 * lane + 256 * k + 2];   // v,t,v,t
    s = fmaf(wv.x, __uint_as_float(p0.x), s);
    s = fmaf(wv.y, __uint_as_float(p0.z), s);
    s = fmaf(wv.z, __uint_as_float(p1.x), s);
    s = fmaf(wv.w, __uint_as_float(p1.z), s);
  }
  #pragma unroll
  for (int sh = 32; sh >= 1; sh >>= 1) s += __shfl_xor(s, sh, 64);
  if (lane == 0) out[o] = s + b_lin[o];
}

// ---------------------------------------------------------------------------
extern "C" void kernel_launch(void* const* d_in, const int* in_sizes, int n_in,
                              void* d_out, int out_size, void* d_ws, size_t ws_size,
                              hipStream_t stream)
{
  const float* input = (const float*)d_in[0];
  const float* W_ih  = (const float*)d_in[1];
  const float* W_hh  = (const float*)d_in[2];
  const float* b_ih  = (const float*)d_in[3];
  const float* b_hh  = (const float*)d_in[4];
  const float* W_lin = (const float*)d_in[5];
  const float* b_lin = (const float*)d_in[6];
  float* out = (float*)d_out;

  char* ws = (char*)d_ws;
  const size_t XG_BYTES = (size_t)T_SEQ * G4 * sizeof(float);   // 128 MB
  float* xg   = (float*)ws;
  uint2* hbuf = (uint2*)(ws + XG_BYTES);

  // 8 replicas if the workspace allows (2 parities x 8 replicas x 2048 pairs
  // x 8B = 256KB), else fall back to the single-copy layout.
  const size_t HB8 = 2ull * 8 * H_DIM * sizeof(uint2);
  int nrep = (ws_size >= XG_BYTES + HB8) ? 8 : 1;
  const size_t HB_BYTES = 2ull * nrep * H_DIM * sizeof(uint2);

  // zero all pair buffers: h_0 = 0 with tag 0 (= step-0 poll target)
  (void)hipMemsetAsync(ws + XG_BYTES, 0, HB_BYTES, stream);

  gemm_xg<<<dim3(64, 32), 256, 0, stream>>>(input, W_ih, b_ih, b_hh, xg);
  lstm_seq<<<256, 512, 0, stream>>>(W_hh, xg, hbuf, nrep);
  proj_out<<<128, 256, 0, stream>>>(W_lin, b_lin, hbuf, out);
}

// Round 10
// 14252.667 us; speedup vs baseline: 1.0007x; 1.0007x over previous
//
#include <hip/hip_runtime.h>
#include <math.h>

#define T_SEQ 4096
#define I_DIM 1024
#define H_DIM 2048
#define O_DIM 512
#define G4    8192   // 4*H

// ---------------------------------------------------------------------------
// Phase 1: xg[t, perm(r)] = sum_k input[t,k]*W_ih[r,k] + b_ih[r] + b_hh[r]
// perm(r): r = g*2048 + 8*q + j  ->  t*8192 + q*32 + g*8 + j
// so that LSTM block b (=q) reads its 32 gate values contiguously.
// Tiled fp32 GEMM: 128x128 tile, BK=16, 256 threads, 8x8 microtile.
// ---------------------------------------------------------------------------
__global__ __launch_bounds__(256) void gemm_xg(
    const float* __restrict__ A, const float* __restrict__ W,
    const float* __restrict__ b_ih, const float* __restrict__ b_hh,
    float* __restrict__ xg)
{
  __shared__ __align__(16) float As[16][132];
  __shared__ __align__(16) float Bs[16][132];
  const int tid = threadIdx.x;
  const int t0 = blockIdx.y * 128;
  const int r0 = blockIdx.x * 128;
  const int tx = tid & 15, ty = tid >> 4;

  float acc[8][8];
  #pragma unroll
  for (int i = 0; i < 8; ++i)
    #pragma unroll
    for (int j = 0; j < 8; ++j) acc[i][j] = 0.f;

  for (int k0 = 0; k0 < I_DIM; k0 += 16) {
    #pragma unroll
    for (int i = 0; i < 2; ++i) {
      int lin = tid + i * 256;     // 0..511
      int row = lin >> 2;          // 0..127
      int kq  = (lin & 3) << 2;    // 0,4,8,12
      float4 va = *(const float4*)&A[(size_t)(t0 + row) * I_DIM + k0 + kq];
      As[kq+0][row] = va.x; As[kq+1][row] = va.y; As[kq+2][row] = va.z; As[kq+3][row] = va.w;
      float4 vb = *(const float4*)&W[(size_t)(r0 + row) * I_DIM + k0 + kq];
      Bs[kq+0][row] = vb.x; Bs[kq+1][row] = vb.y; Bs[kq+2][row] = vb.z; Bs[kq+3][row] = vb.w;
    }
    __syncthreads();
    #pragma unroll
    for (int kk = 0; kk < 16; ++kk) {
      float4 a0 = *(const float4*)&As[kk][ty*8];
      float4 a1 = *(const float4*)&As[kk][ty*8+4];
      float4 b0 = *(const float4*)&Bs[kk][tx*8];
      float4 b1 = *(const float4*)&Bs[kk][tx*8+4];
      float av[8] = {a0.x,a0.y,a0.z,a0.w,a1.x,a1.y,a1.z,a1.w};
      float bv[8] = {b0.x,b0.y,b0.z,b0.w,b1.x,b1.y,b1.z,b1.w};
      #pragma unroll
      for (int i = 0; i < 8; ++i)
        #pragma unroll
        for (int j = 0; j < 8; ++j)
          acc[i][j] = fmaf(av[i], bv[j], acc[i][j]);
    }
    __syncthreads();
  }

  const int rbase = r0 + tx * 8;          // multiple of 8
  const int g = rbase >> 11;              // gate 0..3 (constant over 8 cols)
  const int q = (rbase & 2047) >> 3;      // 8-row group = LSTM block id
  float bias[8];
  #pragma unroll
  for (int j = 0; j < 8; ++j) bias[j] = b_ih[rbase + j] + b_hh[rbase + j];
  #pragma unroll
  for (int i = 0; i < 8; ++i) {
    int t = t0 + ty * 8 + i;
    float* dst = &xg[(size_t)t * G4 + q * 32 + g * 8];
    float4 o0 = make_float4(acc[i][0]+bias[0], acc[i][1]+bias[1], acc[i][2]+bias[2], acc[i][3]+bias[3]);
    float4 o1 = make_float4(acc[i][4]+bias[4], acc[i][5]+bias[5], acc[i][6]+bias[6], acc[i][7]+bias[7]);
    *(float4*)&dst[0] = o0;
    *(float4*)&dst[4] = o1;
  }
}

// fast activations (lane 0 only, but on the serial critical path)
__device__ __forceinline__ float sigf(float x) {
  return 1.f / (1.f + __expf(-x));
}
__device__ __forceinline__ float tanh_fast(float x) {
  return 1.f - 2.f / (__expf(2.f * x) + 1.f);   // saturates correctly
}

// ---------------------------------------------------------------------------
// Phase 2: persistent LSTM recurrence, round-5 sync (self-announcing pairs,
// NREP replicas) + weights truly register-resident.
// Round-9 lesson: the pins compiled but the ALLOCATOR SPILLED them —
// __launch_bounds__(512, 2) caps VGPRs at 128 (2nd arg behaves like CUDA
// min-blocks/CU: 16 waves/CU -> 4 waves/SIMD -> 512/4 = 128), and
// 128 weights + ~60 working regs > 128. VGPR_Count stayed 88, weights sat
// in scratch, and the t-loop re-read 64 MB/step of weights through L2/LLC
// (~24 TB/s = the ~2.6 us/step floor since round 2).
// Fix: __launch_bounds__(512, 1). The 8-wave workgroup still forces the
// compiler to cap at 256 (2 waves/SIMD co-residency), occupancy is
// unchanged (84 KB LDS already pins 1 block/CU), and ~190 live VGPRs now
// fit with NO spill. Pins keep the weights as opaque asm-defined values,
// immune to the poll asm's "memory" clobbers.
// ---------------------------------------------------------------------------
__global__ __launch_bounds__(512, 1) void lstm_seq(
    const float* __restrict__ W_hh, const float* __restrict__ xg,
    uint2* __restrict__ hbuf, int nrep)
{
  __shared__ __align__(16) float smem[21000];  // 84000 B -> forces 1 block/CU
  float* hsh = smem;                           // 2 x 2048 broadcast buffers

  const int tid  = threadIdx.x;
  const int b    = blockIdx.x;     // 0..255
  const int lane = tid & 63;
  const int w    = tid >> 6;       // wave id = h element index within block
  const int pstr = nrep << 11;     // pairs per parity
  const int myrep = b & (nrep - 1);

  // Weights: 4 gate rows of h-element 8b+w; cols 4*lane + 256*k, k=0..7.
  // 32 NAMED float4s, loaded once, pinned into VGPRs.
  const float* wb0 = &W_hh[(size_t)(0 * H_DIM + 8 * b + w) * H_DIM + 4 * lane];
  const float* wb1 = &W_hh[(size_t)(1 * H_DIM + 8 * b + w) * H_DIM + 4 * lane];
  const float* wb2 = &W_hh[(size_t)(2 * H_DIM + 8 * b + w) * H_DIM + 4 * lane];
  const float* wb3 = &W_hh[(size_t)(3 * H_DIM + 8 * b + w) * H_DIM + 4 * lane];

#define WROW(G) \
  float4 w##G##0 = *(const float4*)(wb##G +    0); \
  float4 w##G##1 = *(const float4*)(wb##G +  256); \
  float4 w##G##2 = *(const float4*)(wb##G +  512); \
  float4 w##G##3 = *(const float4*)(wb##G +  768); \
  float4 w##G##4 = *(const float4*)(wb##G + 1024); \
  float4 w##G##5 = *(const float4*)(wb##G + 1280); \
  float4 w##G##6 = *(const float4*)(wb##G + 1536); \
  float4 w##G##7 = *(const float4*)(wb##G + 1792);
  WROW(0) WROW(1) WROW(2) WROW(3)

#define PIN4(V) asm volatile("" : "+v"(V.x), "+v"(V.y), "+v"(V.z), "+v"(V.w));
#define PINROW(G) \
  PIN4(w##G##0) PIN4(w##G##1) PIN4(w##G##2) PIN4(w##G##3) \
  PIN4(w##G##4) PIN4(w##G##5) PIN4(w##G##6) PIN4(w##G##7)
  PINROW(0) PINROW(1) PINROW(2) PINROW(3)

  float c_reg = 0.f;          // cell state (lane 0 of each wave)
  bool gaveup = false;        // hang safety valve

  // preload xg for t = 0 (uniform addresses; only lane 0 consumes)
  const float* xp0 = &xg[(size_t)0 * G4 + b * 32 + w];
  float xgi = xp0[0], xgf = xp0[8], xgg = xp0[16], xgo = xp0[24];

  for (int t = 0; t < T_SEQ; ++t) {
    const uint2* hb = hbuf + (t & 1) * pstr + (myrep << 11);  // my replica of h_t
    const unsigned tag = (unsigned)t;

    // 1) poll my 4 pairs (16B + 16B) until all 4 tags == t
    const uint2* a0 = hb + 256 * w + 4 * lane;
    uint4 f0, f1;
    int tries = 0;
    for (;;) {
      asm volatile("global_load_dwordx4 %0, %2, off sc0 sc1\n\t"
                   "global_load_dwordx4 %1, %3, off sc0 sc1\n\t"
                   "s_waitcnt vmcnt(0)"
                   : "=&v"(f0), "=&v"(f1)
                   : "v"(a0), "v"(a0 + 2)
                   : "memory");
      bool ok = (f0.y == tag) & (f0.w == tag) & (f1.y == tag) & (f1.w == tag);
      if (__all(ok) || gaveup) break;
      if (++tries > (1 << 17)) { gaveup = true; break; }
    }

    // 2) broadcast values into this step's LDS buffer
    float* hd = hsh + ((t & 1) << 11);
    float4 hv4 = make_float4(__uint_as_float(f0.x), __uint_as_float(f0.z),
                             __uint_as_float(f1.x), __uint_as_float(f1.z));
    *(float4*)&hd[256 * w + 4 * lane] = hv4;

    // prefetch xg for step t+1 (independent; consumed at loop tail so the
    // compiler's waitcnt for it lands off the poll path)
    float nxi = 0.f, nxf = 0.f, nxg = 0.f, nxo = 0.f;
    if (t + 1 < T_SEQ) {
      const float* xp = &xg[(size_t)(t + 1) * G4 + b * 32 + w];
      nxi = xp[0]; nxf = xp[8]; nxg = xp[16]; nxo = xp[24];
    }

    __syncthreads();   // the ONE barrier per step

    // 3) dot products: 4 gate rows x 32 cols per lane, weights in VGPRs
    float s0 = 0.f, s1 = 0.f, s2 = 0.f, s3 = 0.f;
#define DOTK(K) { \
    float4 hv = *(const float4*)&hd[4 * lane + 256 * K]; \
    s0 = fmaf(w0##K.x, hv.x, s0); s0 = fmaf(w0##K.y, hv.y, s0); \
    s0 = fmaf(w0##K.z, hv.z, s0); s0 = fmaf(w0##K.w, hv.w, s0); \
    s1 = fmaf(w1##K.x, hv.x, s1); s1 = fmaf(w1##K.y, hv.y, s1); \
    s1 = fmaf(w1##K.z, hv.z, s1); s1 = fmaf(w1##K.w, hv.w, s1); \
    s2 = fmaf(w2##K.x, hv.x, s2); s2 = fmaf(w2##K.y, hv.y, s2); \
    s2 = fmaf(w2##K.z, hv.z, s2); s2 = fmaf(w2##K.w, hv.w, s2); \
    s3 = fmaf(w3##K.x, hv.x, s3); s3 = fmaf(w3##K.y, hv.y, s3); \
    s3 = fmaf(w3##K.z, hv.z, s3); s3 = fmaf(w3##K.w, hv.w, s3); }
    DOTK(0) DOTK(1) DOTK(2) DOTK(3) DOTK(4) DOTK(5) DOTK(6) DOTK(7)

    // butterfly reduce 4 values across 64 lanes
    #pragma unroll
    for (int sh = 32; sh >= 1; sh >>= 1) {
      s0 += __shfl_xor(s0, sh, 64);
      s1 += __shfl_xor(s1, sh, 64);
      s2 += __shfl_xor(s2, sh, 64);
      s3 += __shfl_xor(s3, sh, 64);
    }

    // 4) lane 0: gate math + nrep packed (value, tag) stores (one/replica)
    if (lane == 0) {
      float iv = sigf(s0 + xgi);
      float fv = sigf(s1 + xgf);
      float gv = tanh_fast(s2 + xgg);
      float ov = sigf(s3 + xgo);
      c_reg = fv * c_reg + iv * gv;
      float hv = ov * tanh_fast(c_reg);
      uint2 pv;
      pv.x = __float_as_uint(hv);
      pv.y = (unsigned)(t + 1);
      uint2* dst = hbuf + ((t + 1) & 1) * pstr + 8 * b + w;
      for (int r = 0; r < nrep; ++r) {
        asm volatile("global_store_dwordx2 %0, %1, off sc0 sc1"
                     :: "v"(dst), "v"(pv) : "memory");
        dst += 2048;
      }
    }

    xgi = nxi; xgf = nxf; xgg = nxg; xgo = nxo;
  }
}

// ---------------------------------------------------------------------------
// Phase 3: out[o] = h_last . W_lin[o,:] + b_lin[o]. One wave per output.
// h_last = values of replica-0 pairs at parity 0 (step 4095 writes par 0).
// ---------------------------------------------------------------------------
__global__ __launch_bounds__(256) void proj_out(
    const float* __restrict__ W_lin, const float* __restrict__ b_lin,
    const uint2* __restrict__ hpairs, float* __restrict__ out)
{
  const int tid = threadIdx.x;
  const int lane = tid & 63;
  const int w4 = tid >> 6;
  const int o = blockIdx.x * 4 + w4;
  const float* wr = &W_lin[(size_t)o * H_DIM + 4 * lane];
  float s = 0.f;
  #pragma unroll
  for (int k = 0; k < 8; ++k) {
    float4 wv = *(const float4*)&wr[256 * k];
    uint4 p0 = *(const uint4*)&hpairs[4 * lane + 256 * k];       // v,t,v,t
    uint4 p1 = *(const uint4*)&hpairs[4 * lane + 256 * k + 2];   // v,t,v,t
    s = fmaf(wv.x, __uint_as_float(p0.x), s);
    s = fmaf(wv.y, __uint_as_float(p0.z), s);
    s = fmaf(wv.z, __uint_as_float(p1.x), s);
    s = fmaf(wv.w, __uint_as_float(p1.z), s);
  }
  #pragma unroll
  for (int sh = 32; sh >= 1; sh >>= 1) s += __shfl_xor(s, sh, 64);
  if (lane == 0) out[o] = s + b_lin[o];
}

// ---------------------------------------------------------------------------
extern "C" void kernel_launch(void* const* d_in, const int* in_sizes, int n_in,
                              void* d_out, int out_size, void* d_ws, size_t ws_size,
                              hipStream_t stream)
{
  const float* input = (const float*)d_in[0];
  const float* W_ih  = (const float*)d_in[1];
  const float* W_hh  = (const float*)d_in[2];
  const float* b_ih  = (const float*)d_in[3];
  const float* b_hh  = (const float*)d_in[4];
  const float* W_lin = (const float*)d_in[5];
  const float* b_lin = (const float*)d_in[6];
  float* out = (float*)d_out;

  char* ws = (char*)d_ws;
  const size_t XG_BYTES = (size_t)T_SEQ * G4 * sizeof(float);   // 128 MB
  float* xg   = (float*)ws;
  uint2* hbuf = (uint2*)(ws + XG_BYTES);

  // 8 replicas if the workspace allows (2 parities x 8 replicas x 2048 pairs
  // x 8B = 256KB), else fall back to the single-copy layout.
  const size_t HB8 = 2ull * 8 * H_DIM * sizeof(uint2);
  int nrep = (ws_size >= XG_BYTES + HB8) ? 8 : 1;
  const size_t HB_BYTES = 2ull * nrep * H_DIM * sizeof(uint2);

  // zero all pair buffers: h_0 = 0 with tag 0 (= step-0 poll target)
  (void)hipMemsetAsync(ws + XG_BYTES, 0, HB_BYTES, stream);

  gemm_xg<<<dim3(64, 32), 256, 0, stream>>>(input, W_ih, b_ih, b_hh, xg);
  lstm_seq<<<256, 512, 0, stream>>>(W_hh, xg, hbuf, nrep);
  proj_out<<<128, 256, 0, stream>>>(W_lin, b_lin, hbuf, out);
}